// Round 1
// baseline (773.712 us; speedup 1.0000x reference)
//
#include <hip/hip_runtime.h>
#include <hip/hip_bf16.h>
#include <math.h>

// Problem constants (match reference)
#define NNODES 50000
#define NEDGES 800000
#define INF 128
#define OUTF 128
#define HEADS 2
#define NEG_SLOPE 0.2f

// ---------- helpers: order-preserving float<->uint for atomicMax ----------
__device__ __forceinline__ unsigned f2o(float f) {
    unsigned u = __float_as_uint(f);
    return (u & 0x80000000u) ? ~u : (u | 0x80000000u);
}
__device__ __forceinline__ float o2f(unsigned u) {
    u = (u & 0x80000000u) ? (u & 0x7FFFFFFFu) : ~u;
    return __uint_as_float(u);
}
#define EMAX_INIT 0x007FFFFFu   // == f2o(-inf)

// ---------- K0: init scratch (ws is poisoned 0xAA every call) ----------
__global__ void init_kernel(unsigned* emax_u, float* denom, int* count, int NH, int Np1) {
    int i = blockIdx.x * 256 + threadIdx.x;
    if (i < NH) { emax_u[i] = EMAX_INIT; denom[i] = 0.0f; }
    if (i < Np1) count[i] = 0;
}

// ---------- K1: ft[n][j] = sum_f feat[n][f] * Wcat[j][f]  (j = h*128+o) ----------
// 64x64 tile, K=128 in two 64-chunks, k-major LDS (conflict-free compute reads)
__global__ __launch_bounds__(256) void gemm_ft(const float* __restrict__ feat,
                                               const float* __restrict__ W,
                                               float* __restrict__ ft, int N) {
    __shared__ float As[64][68];  // [k][n], row 68 floats keeps 16B alignment
    __shared__ float Bs[64][68];  // [k][j]
    const int t = threadIdx.x;
    const int n0 = blockIdx.x * 64;
    const int j0 = blockIdx.y * 64;
    const int tm = t >> 4, tn = t & 15;
    float acc[4][4] = {};

    for (int kc = 0; kc < 2; ++kc) {
        // stage: 64 rows x 64 k-cols = 1024 float4 loads, 4 per thread
#pragma unroll
        for (int i = 0; i < 4; ++i) {
            int q  = t + i * 256;       // 0..1023
            int r  = q >> 4;            // row (n or j), 0..63
            int f4 = q & 15;            // k-offset/4
            float4 g = make_float4(0.f, 0.f, 0.f, 0.f);
            int gn = n0 + r;
            if (gn < N) g = *(const float4*)(feat + (size_t)gn * INF + kc * 64 + f4 * 4);
            As[f4 * 4 + 0][r] = g.x; As[f4 * 4 + 1][r] = g.y;
            As[f4 * 4 + 2][r] = g.z; As[f4 * 4 + 3][r] = g.w;
            float4 b = *(const float4*)(W + (size_t)(j0 + r) * INF + kc * 64 + f4 * 4);
            Bs[f4 * 4 + 0][r] = b.x; Bs[f4 * 4 + 1][r] = b.y;
            Bs[f4 * 4 + 2][r] = b.z; Bs[f4 * 4 + 3][r] = b.w;
        }
        __syncthreads();
#pragma unroll 4
        for (int kk = 0; kk < 64; ++kk) {
            float4 a4 = *(const float4*)(&As[kk][tm * 4]);
            float4 b4 = *(const float4*)(&Bs[kk][tn * 4]);
            acc[0][0] += a4.x * b4.x; acc[0][1] += a4.x * b4.y; acc[0][2] += a4.x * b4.z; acc[0][3] += a4.x * b4.w;
            acc[1][0] += a4.y * b4.x; acc[1][1] += a4.y * b4.y; acc[1][2] += a4.y * b4.z; acc[1][3] += a4.y * b4.w;
            acc[2][0] += a4.z * b4.x; acc[2][1] += a4.z * b4.y; acc[2][2] += a4.z * b4.z; acc[2][3] += a4.z * b4.w;
            acc[3][0] += a4.w * b4.x; acc[3][1] += a4.w * b4.y; acc[3][2] += a4.w * b4.z; acc[3][3] += a4.w * b4.w;
        }
        __syncthreads();
    }
#pragma unroll
    for (int i = 0; i < 4; ++i) {
        int gn = n0 + tm * 4 + i;
        if (gn < N) {
            float4 r = make_float4(acc[i][0], acc[i][1], acc[i][2], acc[i][3]);
            *(float4*)(ft + (size_t)gn * 256 + j0 + tn * 4) = r;
        }
    }
}

// ---------- K2: el/er per node (one wave per node) ----------
__global__ __launch_bounds__(256) void compute_eler(const float* __restrict__ ft,
                                                    const float* __restrict__ attn_l,
                                                    const float* __restrict__ attn_r,
                                                    float* __restrict__ el, float* __restrict__ er, int N) {
    int wave = threadIdx.x >> 6;
    int lane = threadIdx.x & 63;
    int n = blockIdx.x * 4 + wave;
    if (n >= N) return;
    float4 f  = *(const float4*)(ft + (size_t)n * 256 + lane * 4);
    float4 al = *(const float4*)(attn_l + lane * 4);
    float4 ar = *(const float4*)(attn_r + lane * 4);
    float pl = f.x * al.x + f.y * al.y + f.z * al.z + f.w * al.w;
    float pr = f.x * ar.x + f.y * ar.y + f.z * ar.z + f.w * ar.w;
#pragma unroll
    for (int off = 1; off < 32; off <<= 1) {
        pl += __shfl_xor(pl, off, 64);
        pr += __shfl_xor(pr, off, 64);
    }
    if ((lane & 31) == 0) {
        int h = lane >> 5;
        el[n * 2 + h] = pl;
        er[n * 2 + h] = pr;
    }
}

// ---------- K3: edge logits + leaky_relu + segment max + degree count ----------
__global__ void edge_logits(const float* __restrict__ el, const float* __restrict__ er,
                            const float* __restrict__ e_w, const int* __restrict__ src,
                            const int* __restrict__ dst, const float* __restrict__ attn_ew,
                            float* __restrict__ e_val, unsigned* __restrict__ emax_u,
                            int* __restrict__ count, int E) {
    int e = blockIdx.x * 256 + threadIdx.x;
    if (e >= E) return;
    int s = src[e], d = dst[e];
    float2 ew2 = *(const float2*)(e_w + (size_t)e * 2);
    float2 els = *(const float2*)(el + (size_t)s * 2);
    float2 erd = *(const float2*)(er + (size_t)d * 2);
    float v0 = els.x + erd.x + ew2.x * attn_ew[0] + ew2.y * attn_ew[1];
    float v1 = els.y + erd.y + ew2.x * attn_ew[2] + ew2.y * attn_ew[3];
    v0 = v0 >= 0.f ? v0 : NEG_SLOPE * v0;
    v1 = v1 >= 0.f ? v1 : NEG_SLOPE * v1;
    *(float2*)(e_val + (size_t)e * 2) = make_float2(v0, v1);
    atomicMax(emax_u + d * 2 + 0, f2o(v0));
    atomicMax(emax_u + d * 2 + 1, f2o(v1));
    atomicAdd(count + d, 1);
}

// ---------- K4: exclusive scan of degree counts -> CSR offsets (single block) ----------
__global__ __launch_bounds__(1024) void scan_kernel(const int* __restrict__ count,
                                                    int* __restrict__ offs,
                                                    int* __restrict__ cursor, int N) {
    __shared__ int ssum[1024];
    const int t = threadIdx.x;
    const int C = (N + 1023) / 1024;
    int lo = t * C;
    int hi = lo + C; if (hi > N) hi = N;
    int s = 0;
    for (int j = lo; j < hi; ++j) s += count[j];
    ssum[t] = s;
    __syncthreads();
    for (int off = 1; off < 1024; off <<= 1) {
        int x = (t >= off) ? ssum[t - off] : 0;
        __syncthreads();
        ssum[t] += x;
        __syncthreads();
    }
    int run = ssum[t] - s;   // exclusive prefix
    for (int j = lo; j < hi; ++j) {
        offs[j] = run; cursor[j] = run;
        run += count[j];
    }
    if (t == 1023) offs[N] = ssum[1023];
}

// ---------- K5: softmax numerator + denom + CSR scatter ----------
__global__ void softmax_scatter(const int* __restrict__ dst, const unsigned* __restrict__ emax_u,
                                float* __restrict__ e_val, float* __restrict__ denom,
                                int* __restrict__ cursor, int* __restrict__ sorted_eid, int E) {
    int e = blockIdx.x * 256 + threadIdx.x;
    if (e >= E) return;
    int d = dst[e];
    float2 v = *(const float2*)(e_val + (size_t)e * 2);
    float m0 = o2f(emax_u[d * 2 + 0]);
    float m1 = o2f(emax_u[d * 2 + 1]);
    float ee0 = __expf(v.x - m0);
    float ee1 = __expf(v.y - m1);
    *(float2*)(e_val + (size_t)e * 2) = make_float2(ee0, ee1);
    atomicAdd(denom + d * 2 + 0, ee0);
    atomicAdd(denom + d * 2 + 1, ee1);
    int pos = atomicAdd(cursor + d, 1);
    sorted_eid[pos] = e;
}

// ---------- K6: per-dst gather-aggregate + residual + elu ----------
__global__ __launch_bounds__(256) void aggregate(const float* __restrict__ ft,
                                                 const float* __restrict__ feat,
                                                 const float* __restrict__ e_val,
                                                 const float* __restrict__ denom,
                                                 const int* __restrict__ offs,
                                                 const int* __restrict__ sorted_eid,
                                                 const int* __restrict__ src,
                                                 float* __restrict__ out, int N) {
    int n = blockIdx.x;
    int t = threadIdx.x;           // t = h*128 + o
    int o0 = offs[n], o1 = offs[n + 1];
    float2 dn = *(const float2*)(denom + (size_t)n * 2);
    float inv0 = dn.x > 0.f ? 1.0f / dn.x : 1.0f;
    float inv1 = dn.y > 0.f ? 1.0f / dn.y : 1.0f;
    float acc = 0.0f;
    for (int i = o0; i < o1; ++i) {
        int eid = sorted_eid[i];
        int s = src[eid];
        float2 ee = *(const float2*)(e_val + (size_t)eid * 2);
        float a = (t < 128) ? ee.x * inv0 : ee.y * inv1;   // wave-uniform select
        acc += a * ft[(size_t)s * 256 + t];
    }
    float r = acc + feat[(size_t)n * INF + (t & 127)];
    out[(size_t)n * 256 + t] = r > 0.f ? r : expm1f(r);
}

extern "C" void kernel_launch(void* const* d_in, const int* in_sizes, int n_in,
                              void* d_out, int out_size, void* d_ws, size_t ws_size,
                              hipStream_t stream) {
    const float* feat    = (const float*)d_in[0];
    const float* e_w     = (const float*)d_in[1];
    const int*   src     = (const int*)d_in[2];
    const int*   dst     = (const int*)d_in[3];
    const float* W       = (const float*)d_in[4];
    const float* attn_l  = (const float*)d_in[5];
    const float* attn_r  = (const float*)d_in[6];
    const float* attn_ew = (const float*)d_in[7];
    float* out = (float*)d_out;

    const int N = in_sizes[0] / INF;   // 50000
    const int E = in_sizes[2];         // 800000

    // workspace carve-up (all 16B-aligned given sizes)
    float*    ft      = (float*)d_ws;              // N*256
    float*    el      = ft + (size_t)N * 256;      // N*2
    float*    er      = el + (size_t)N * 2;        // N*2
    float*    e_val   = er + (size_t)N * 2;        // E*2
    float*    denom   = e_val + (size_t)E * 2;     // N*2
    unsigned* emax_u  = (unsigned*)(denom + (size_t)N * 2);  // N*2
    int*      count   = (int*)(emax_u + (size_t)N * 2);      // N+1
    int*      offs    = count + (N + 1);           // N+1
    int*      cursor  = offs + (N + 1);            // N
    int*      sorted  = cursor + N;                // E

    const int NH = N * HEADS;
    int initN = (NH > N + 1) ? NH : (N + 1);

    init_kernel<<<(initN + 255) / 256, 256, 0, stream>>>(emax_u, denom, count, NH, N + 1);

    dim3 ggrid((N + 63) / 64, 4);
    gemm_ft<<<ggrid, 256, 0, stream>>>(feat, W, ft, N);

    compute_eler<<<(N + 3) / 4, 256, 0, stream>>>(ft, attn_l, attn_r, el, er, N);

    edge_logits<<<(E + 255) / 256, 256, 0, stream>>>(el, er, e_w, src, dst, attn_ew,
                                                     e_val, emax_u, count, E);

    scan_kernel<<<1, 1024, 0, stream>>>(count, offs, cursor, N);

    softmax_scatter<<<(E + 255) / 256, 256, 0, stream>>>(dst, emax_u, e_val, denom,
                                                         cursor, sorted, E);

    aggregate<<<N, 256, 0, stream>>>(ft, feat, e_val, denom, offs, sorted, src, out, N);
}

// Round 2
// 517.434 us; speedup vs baseline: 1.4953x; 1.4953x over previous
//
#include <hip/hip_runtime.h>
#include <hip/hip_bf16.h>
#include <math.h>

// Problem constants (match reference)
#define NNODES 50000
#define NEDGES 800000
#define INF 128
#define OUTF 128
#define HEADS 2
#define NEG_SLOPE 0.2f

__device__ __forceinline__ unsigned short f2bf(float f) {
    unsigned u = __float_as_uint(f);
    unsigned r = (u + 0x7FFFu + ((u >> 16) & 1u)) >> 16;   // RNE
    return (unsigned short)r;
}
__device__ __forceinline__ float bf2f(unsigned short b) {
    return __uint_as_float((unsigned)b << 16);
}

// ---------- K0: init scratch (ws is poisoned 0xAA every call) ----------
__global__ void init_kernel(float* el, float* er, float* denom, int* count, int NH, int Np1) {
    int i = blockIdx.x * 256 + threadIdx.x;
    if (i < NH) { el[i] = 0.f; er[i] = 0.f; denom[i] = 0.f; }
    if (i < Np1) count[i] = 0;
}

// ---------- K1: ft = feat @ Wcat^T (fp32 acc, bf16 store) + fused el/er ----------
// 64x64 tile, K=128 in two 64-chunks, k-major LDS (conflict-free compute reads).
// el/er computed from fp32 accumulators (exact logits), reduced via shuffle + atomicAdd.
__global__ __launch_bounds__(256) void gemm_ft(const float* __restrict__ feat,
                                               const float* __restrict__ W,
                                               const float* __restrict__ attn_l,
                                               const float* __restrict__ attn_r,
                                               unsigned short* __restrict__ ftb,
                                               float* __restrict__ el, float* __restrict__ er,
                                               int N) {
    __shared__ float As[64][68];  // [k][n]
    __shared__ float Bs[64][68];  // [k][j]
    const int t = threadIdx.x;
    const int n0 = blockIdx.x * 64;
    const int j0 = blockIdx.y * 64;     // 0,64,128,192 ; head = j0>>7
    const int tm = t >> 4, tn = t & 15;
    float acc[4][4] = {};

    for (int kc = 0; kc < 2; ++kc) {
#pragma unroll
        for (int i = 0; i < 4; ++i) {
            int q  = t + i * 256;
            int r  = q >> 4;
            int f4 = q & 15;
            float4 g = make_float4(0.f, 0.f, 0.f, 0.f);
            int gn = n0 + r;
            if (gn < N) g = *(const float4*)(feat + (size_t)gn * INF + kc * 64 + f4 * 4);
            As[f4 * 4 + 0][r] = g.x; As[f4 * 4 + 1][r] = g.y;
            As[f4 * 4 + 2][r] = g.z; As[f4 * 4 + 3][r] = g.w;
            float4 b = *(const float4*)(W + (size_t)(j0 + r) * INF + kc * 64 + f4 * 4);
            Bs[f4 * 4 + 0][r] = b.x; Bs[f4 * 4 + 1][r] = b.y;
            Bs[f4 * 4 + 2][r] = b.z; Bs[f4 * 4 + 3][r] = b.w;
        }
        __syncthreads();
#pragma unroll 4
        for (int kk = 0; kk < 64; ++kk) {
            float4 a4 = *(const float4*)(&As[kk][tm * 4]);
            float4 b4 = *(const float4*)(&Bs[kk][tn * 4]);
            acc[0][0] += a4.x * b4.x; acc[0][1] += a4.x * b4.y; acc[0][2] += a4.x * b4.z; acc[0][3] += a4.x * b4.w;
            acc[1][0] += a4.y * b4.x; acc[1][1] += a4.y * b4.y; acc[1][2] += a4.y * b4.z; acc[1][3] += a4.y * b4.w;
            acc[2][0] += a4.z * b4.x; acc[2][1] += a4.z * b4.y; acc[2][2] += a4.z * b4.z; acc[2][3] += a4.z * b4.w;
            acc[3][0] += a4.w * b4.x; acc[3][1] += a4.w * b4.y; acc[3][2] += a4.w * b4.z; acc[3][3] += a4.w * b4.w;
        }
        __syncthreads();
    }

    // attn vectors for this tile's 4 columns: flat index = j0 + tn*4 (j0 already h*128+off)
    float4 al = *(const float4*)(attn_l + j0 + tn * 4);
    float4 ar = *(const float4*)(attn_r + j0 + tn * 4);
    const int h = j0 >> 7;

#pragma unroll
    for (int i = 0; i < 4; ++i) {
        int gn = n0 + tm * 4 + i;
        float pl = acc[i][0] * al.x + acc[i][1] * al.y + acc[i][2] * al.z + acc[i][3] * al.w;
        float pr = acc[i][0] * ar.x + acc[i][1] * ar.y + acc[i][2] * ar.z + acc[i][3] * ar.w;
        // reduce across the 16 tn lanes (xor masks stay within the tn group)
#pragma unroll
        for (int m = 1; m < 16; m <<= 1) {
            pl += __shfl_xor(pl, m, 64);
            pr += __shfl_xor(pr, m, 64);
        }
        if (gn < N) {
            if (tn == 0) {
                atomicAdd(el + gn * 2 + h, pl);
                atomicAdd(er + gn * 2 + h, pr);
            }
            ushort4 v;
            v.x = f2bf(acc[i][0]); v.y = f2bf(acc[i][1]);
            v.z = f2bf(acc[i][2]); v.w = f2bf(acc[i][3]);
            *(ushort4*)(ftb + (size_t)gn * 256 + j0 + tn * 4) = v;
        }
    }
}

// ---------- K2: edge logits + leaky_relu + exp + denom + degree count ----------
// (segment-max skipped: logits are O(10), exp safe in fp32; softmax shift-invariant)
__global__ void edge_logits(const float* __restrict__ el, const float* __restrict__ er,
                            const float* __restrict__ e_w, const int* __restrict__ src,
                            const int* __restrict__ dst, const float* __restrict__ attn_ew,
                            float* __restrict__ e_val, float* __restrict__ denom,
                            int* __restrict__ count, int E) {
    int e = blockIdx.x * 256 + threadIdx.x;
    if (e >= E) return;
    int s = src[e], d = dst[e];
    float2 ew2 = *(const float2*)(e_w + (size_t)e * 2);
    float2 els = *(const float2*)(el + (size_t)s * 2);
    float2 erd = *(const float2*)(er + (size_t)d * 2);
    float v0 = els.x + erd.x + ew2.x * attn_ew[0] + ew2.y * attn_ew[1];
    float v1 = els.y + erd.y + ew2.x * attn_ew[2] + ew2.y * attn_ew[3];
    v0 = v0 >= 0.f ? v0 : NEG_SLOPE * v0;
    v1 = v1 >= 0.f ? v1 : NEG_SLOPE * v1;
    float ee0 = __expf(v0);
    float ee1 = __expf(v1);
    *(float2*)(e_val + (size_t)e * 2) = make_float2(ee0, ee1);
    atomicAdd(denom + d * 2 + 0, ee0);
    atomicAdd(denom + d * 2 + 1, ee1);
    atomicAdd(count + d, 1);
}

// ---------- K3: exclusive scan of degree counts -> CSR offsets (single block) ----------
__global__ __launch_bounds__(1024) void scan_kernel(const int* __restrict__ count,
                                                    int* __restrict__ offs,
                                                    int* __restrict__ cursor, int N) {
    __shared__ int ssum[1024];
    const int t = threadIdx.x;
    const int C = (N + 1023) / 1024;
    int lo = t * C;
    int hi = lo + C; if (hi > N) hi = N;
    int s = 0;
    for (int j = lo; j < hi; ++j) s += count[j];
    ssum[t] = s;
    __syncthreads();
    for (int off = 1; off < 1024; off <<= 1) {
        int x = (t >= off) ? ssum[t - off] : 0;
        __syncthreads();
        ssum[t] += x;
        __syncthreads();
    }
    int run = ssum[t] - s;   // exclusive prefix
    for (int j = lo; j < hi; ++j) {
        offs[j] = run; cursor[j] = run;
        run += count[j];
    }
    if (t == 1023) offs[N] = ssum[1023];
}

// ---------- K4: scatter (src, ee) into CSR order ----------
__global__ void scatter_kernel(const int* __restrict__ src, const int* __restrict__ dst,
                               const float* __restrict__ e_val, int* __restrict__ cursor,
                               int* __restrict__ srcsorted, float* __restrict__ eesorted, int E) {
    int e = blockIdx.x * 256 + threadIdx.x;
    if (e >= E) return;
    int d = dst[e];
    float2 ee = *(const float2*)(e_val + (size_t)e * 2);
    int pos = atomicAdd(cursor + d, 1);
    srcsorted[pos] = src[e];
    *(float2*)(eesorted + (size_t)pos * 2) = ee;
}

// ---------- K5: per-dst gather-aggregate (bf16 ft) + residual + elu ----------
#define CHUNK 128
__global__ __launch_bounds__(256) void aggregate(const unsigned short* __restrict__ ftb,
                                                 const float* __restrict__ feat,
                                                 const float* __restrict__ denom,
                                                 const int* __restrict__ offs,
                                                 const int* __restrict__ srcsorted,
                                                 const float* __restrict__ eesorted,
                                                 float* __restrict__ out, int N) {
    __shared__ int   s_sh[CHUNK];
    __shared__ float a0_sh[CHUNK];
    __shared__ float a1_sh[CHUNK];
    __shared__ float red[4][256];
    const int n = blockIdx.x;
    const int t = threadIdx.x;
    const int w = t >> 6, l = t & 63;
    const int o0 = offs[n], o1 = offs[n + 1];
    float2 dn = *(const float2*)(denom + (size_t)n * 2);
    float inv0 = dn.x > 0.f ? 1.0f / dn.x : 1.0f;
    float inv1 = dn.y > 0.f ? 1.0f / dn.y : 1.0f;
    float4 acc = make_float4(0.f, 0.f, 0.f, 0.f);
    const int c0 = 4 * l;                       // this lane's 4 columns
    const float* a_sel_base = (l < 32) ? a0_sh : a1_sh;

    for (int base = o0; base < o1; base += CHUNK) {
        int cnt = o1 - base; if (cnt > CHUNK) cnt = CHUNK;
        for (int i = t; i < cnt; i += 256) {
            s_sh[i] = srcsorted[base + i];
            float2 ee = *(const float2*)(eesorted + (size_t)(base + i) * 2);
            a0_sh[i] = ee.x * inv0;
            a1_sh[i] = ee.y * inv1;
        }
        __syncthreads();
        for (int i = w; i < cnt; i += 4) {
            int s = s_sh[i];
            float a = a_sel_base[i];
            ushort4 v = *(const ushort4*)(ftb + (size_t)s * 256 + c0);
            acc.x += a * bf2f(v.x);
            acc.y += a * bf2f(v.y);
            acc.z += a * bf2f(v.z);
            acc.w += a * bf2f(v.w);
        }
        __syncthreads();
    }
    *(float4*)(&red[w][c0]) = acc;
    __syncthreads();
    float r = red[0][t] + red[1][t] + red[2][t] + red[3][t];
    r += feat[(size_t)n * INF + (t & 127)];
    out[(size_t)n * 256 + t] = r > 0.f ? r : expm1f(r);
}

extern "C" void kernel_launch(void* const* d_in, const int* in_sizes, int n_in,
                              void* d_out, int out_size, void* d_ws, size_t ws_size,
                              hipStream_t stream) {
    const float* feat    = (const float*)d_in[0];
    const float* e_w     = (const float*)d_in[1];
    const int*   src     = (const int*)d_in[2];
    const int*   dst     = (const int*)d_in[3];
    const float* W       = (const float*)d_in[4];
    const float* attn_l  = (const float*)d_in[5];
    const float* attn_r  = (const float*)d_in[6];
    const float* attn_ew = (const float*)d_in[7];
    float* out = (float*)d_out;

    const int N = in_sizes[0] / INF;   // 50000
    const int E = in_sizes[2];         // 800000

    // workspace carve-up (all 16B-aligned given these sizes)
    unsigned short* ftb = (unsigned short*)d_ws;            // N*256 bf16
    float* el       = (float*)(ftb + (size_t)N * 256);      // N*2
    float* er       = el + (size_t)N * 2;                   // N*2
    float* e_val    = er + (size_t)N * 2;                   // E*2
    float* denom    = e_val + (size_t)E * 2;                // N*2
    float* eesorted = denom + (size_t)N * 2;                // E*2
    int*   count    = (int*)(eesorted + (size_t)E * 2);     // N+1
    int*   offs     = count + (N + 1);                      // N+1
    int*   cursor   = offs + (N + 1);                       // N
    int*   srcsorted= cursor + N;                           // E

    const int NH = N * HEADS;
    int initN = (NH > N + 1) ? NH : (N + 1);

    init_kernel<<<(initN + 255) / 256, 256, 0, stream>>>(el, er, denom, count, NH, N + 1);

    dim3 ggrid((N + 63) / 64, 4);
    gemm_ft<<<ggrid, 256, 0, stream>>>(feat, W, attn_l, attn_r, ftb, el, er, N);

    edge_logits<<<(E + 255) / 256, 256, 0, stream>>>(el, er, e_w, src, dst, attn_ew,
                                                     e_val, denom, count, E);

    scan_kernel<<<1, 1024, 0, stream>>>(count, offs, cursor, N);

    scatter_kernel<<<(E + 255) / 256, 256, 0, stream>>>(src, dst, e_val, cursor,
                                                        srcsorted, eesorted, E);

    aggregate<<<N, 256, 0, stream>>>(ftb, feat, denom, offs, srcsorted, eesorted, out, N);
}

// Round 3
// 303.747 us; speedup vs baseline: 2.5472x; 1.7035x over previous
//
#include <hip/hip_runtime.h>
#include <hip/hip_bf16.h>
#include <math.h>

// Problem constants (match reference)
#define NNODES 50000
#define NEDGES 800000
#define INF 128
#define OUTF 128
#define HEADS 2
#define NEG_SLOPE 0.2f

// Padded-bin CSR: mean degree = 16 (Poisson), CAP=32 overflows on ~1e-4 of
// nodes; overflow edges go to a small list handled exactly in aggregate.
#define CAP 32
#define OVFCAP 32768

__device__ __forceinline__ unsigned short f2bf(float f) {
    unsigned u = __float_as_uint(f);
    unsigned r = (u + 0x7FFFu + ((u >> 16) & 1u)) >> 16;   // RNE
    return (unsigned short)r;
}
__device__ __forceinline__ float bf2f(unsigned short b) {
    return __uint_as_float((unsigned)b << 16);
}

// ---------- K0: init scratch (ws is poisoned 0xAA every call) ----------
__global__ void init_kernel(int* cursor, int* ovfcnt, int N) {
    int i = blockIdx.x * 256 + threadIdx.x;
    if (i < N) cursor[i] = 0;
    if (i == 0) *ovfcnt = 0;
}

// ---------- K1: ft = feat @ Wcat^T (fp32 acc, bf16 store) + el/er partials ----------
// 64x64 tile, K=128 in two 64-chunks, k-major LDS (conflict-free compute reads).
// el/er partials (this block's 64-dim slice of head h) stored non-atomically to
// slice q = (j0>>6)&1 ; edge kernel sums the two slices.
__global__ __launch_bounds__(256) void gemm_ft(const float* __restrict__ feat,
                                               const float* __restrict__ W,
                                               const float* __restrict__ attn_l,
                                               const float* __restrict__ attn_r,
                                               unsigned short* __restrict__ ftb,
                                               float* __restrict__ elp, float* __restrict__ erp,
                                               int N) {
    __shared__ float As[64][68];  // [k][n]
    __shared__ float Bs[64][68];  // [k][j]
    const int t = threadIdx.x;
    const int n0 = blockIdx.x * 64;
    const int j0 = blockIdx.y * 64;     // 0,64,128,192 ; head = j0>>7, slice q=(j0>>6)&1
    const int tm = t >> 4, tn = t & 15;
    float acc[4][4] = {};

    for (int kc = 0; kc < 2; ++kc) {
#pragma unroll
        for (int i = 0; i < 4; ++i) {
            int q  = t + i * 256;
            int r  = q >> 4;
            int f4 = q & 15;
            float4 g = make_float4(0.f, 0.f, 0.f, 0.f);
            int gn = n0 + r;
            if (gn < N) g = *(const float4*)(feat + (size_t)gn * INF + kc * 64 + f4 * 4);
            As[f4 * 4 + 0][r] = g.x; As[f4 * 4 + 1][r] = g.y;
            As[f4 * 4 + 2][r] = g.z; As[f4 * 4 + 3][r] = g.w;
            float4 b = *(const float4*)(W + (size_t)(j0 + r) * INF + kc * 64 + f4 * 4);
            Bs[f4 * 4 + 0][r] = b.x; Bs[f4 * 4 + 1][r] = b.y;
            Bs[f4 * 4 + 2][r] = b.z; Bs[f4 * 4 + 3][r] = b.w;
        }
        __syncthreads();
#pragma unroll 4
        for (int kk = 0; kk < 64; ++kk) {
            float4 a4 = *(const float4*)(&As[kk][tm * 4]);
            float4 b4 = *(const float4*)(&Bs[kk][tn * 4]);
            acc[0][0] += a4.x * b4.x; acc[0][1] += a4.x * b4.y; acc[0][2] += a4.x * b4.z; acc[0][3] += a4.x * b4.w;
            acc[1][0] += a4.y * b4.x; acc[1][1] += a4.y * b4.y; acc[1][2] += a4.y * b4.z; acc[1][3] += a4.y * b4.w;
            acc[2][0] += a4.z * b4.x; acc[2][1] += a4.z * b4.y; acc[2][2] += a4.z * b4.z; acc[2][3] += a4.z * b4.w;
            acc[3][0] += a4.w * b4.x; acc[3][1] += a4.w * b4.y; acc[3][2] += a4.w * b4.z; acc[3][3] += a4.w * b4.w;
        }
        __syncthreads();
    }

    float4 al = *(const float4*)(attn_l + j0 + tn * 4);
    float4 ar = *(const float4*)(attn_r + j0 + tn * 4);
    const int h = j0 >> 7;
    const int q = (j0 >> 6) & 1;
    const size_t slice = (size_t)q * (size_t)N * 2;

#pragma unroll
    for (int i = 0; i < 4; ++i) {
        int gn = n0 + tm * 4 + i;
        float pl = acc[i][0] * al.x + acc[i][1] * al.y + acc[i][2] * al.z + acc[i][3] * al.w;
        float pr = acc[i][0] * ar.x + acc[i][1] * ar.y + acc[i][2] * ar.z + acc[i][3] * ar.w;
#pragma unroll
        for (int m = 1; m < 16; m <<= 1) {
            pl += __shfl_xor(pl, m, 64);
            pr += __shfl_xor(pr, m, 64);
        }
        if (gn < N) {
            if (tn == 0) {
                elp[slice + (size_t)gn * 2 + h] = pl;
                erp[slice + (size_t)gn * 2 + h] = pr;
            }
            ushort4 v;
            v.x = f2bf(acc[i][0]); v.y = f2bf(acc[i][1]);
            v.z = f2bf(acc[i][2]); v.w = f2bf(acc[i][3]);
            *(ushort4*)(ftb + (size_t)gn * 256 + j0 + tn * 4) = v;
        }
    }
}

// ---------- K2: fused edge logits + leaky_relu + exp + padded-bin scatter ----------
// No segment-max (softmax shift-invariant; logits O(10), exp safe in fp32).
// One atomic per edge.
__global__ void edge_fused(const float* __restrict__ elp, const float* __restrict__ erp,
                           const float* __restrict__ e_w, const int* __restrict__ src,
                           const int* __restrict__ dst, const float* __restrict__ attn_ew,
                           int* __restrict__ cursor, int* __restrict__ ovfcnt,
                           float4* __restrict__ edata, float4* __restrict__ ovf,
                           int E, int N) {
    int e = blockIdx.x * 256 + threadIdx.x;
    if (e >= E) return;
    const size_t N2 = (size_t)N * 2;
    int s = src[e], d = dst[e];
    float2 ew2 = *(const float2*)(e_w + (size_t)e * 2);
    float2 eA = *(const float2*)(elp + (size_t)s * 2);
    float2 eB = *(const float2*)(elp + N2 + (size_t)s * 2);
    float2 rA = *(const float2*)(erp + (size_t)d * 2);
    float2 rB = *(const float2*)(erp + N2 + (size_t)d * 2);
    float v0 = eA.x + eB.x + rA.x + rB.x + ew2.x * attn_ew[0] + ew2.y * attn_ew[1];
    float v1 = eA.y + eB.y + rA.y + rB.y + ew2.x * attn_ew[2] + ew2.y * attn_ew[3];
    v0 = v0 >= 0.f ? v0 : NEG_SLOPE * v0;
    v1 = v1 >= 0.f ? v1 : NEG_SLOPE * v1;
    float ee0 = __expf(v0);
    float ee1 = __expf(v1);
    int pos = atomicAdd(cursor + d, 1);
    if (pos < CAP) {
        edata[(size_t)d * CAP + pos] = make_float4(__int_as_float(s), ee0, ee1, 0.f);
    } else {
        int o = atomicAdd(ovfcnt, 1);
        if (o < OVFCAP)
            ovf[o] = make_float4(__int_as_float(d), __int_as_float(s), ee0, ee1);
    }
}

// ---------- K3: per-dst gather-aggregate (bf16 ft) + softmax-normalize + residual + elu ----------
__global__ __launch_bounds__(256) void aggregate(const unsigned short* __restrict__ ftb,
                                                 const float* __restrict__ feat,
                                                 const float4* __restrict__ edata,
                                                 const int* __restrict__ cursor,
                                                 const int* __restrict__ ovfcnt,
                                                 const float4* __restrict__ ovf,
                                                 float* __restrict__ out, int N) {
    __shared__ float red[4][256];
    __shared__ float dnw[4][2];
    const int n = blockIdx.x;
    const int t = threadIdx.x;
    const int w = t >> 6, l = t & 63;
    const int c0 = 4 * l;            // this lane's 4 columns (0..252)
    const int h = l >> 5;            // lane's head
    const int cnt = cursor[n];
    const int cmain = cnt < CAP ? cnt : CAP;
    const float4* eb = edata + (size_t)n * CAP;

    float4 acc = make_float4(0.f, 0.f, 0.f, 0.f);
    float dn = 0.f;
    for (int i = w; i < cmain; i += 4) {
        float4 ed = eb[i];                       // wave-uniform addr -> broadcast
        int s = __float_as_int(ed.x);
        float a = h ? ed.z : ed.y;
        dn += a;
        ushort4 v = *(const ushort4*)(ftb + (size_t)s * 256 + c0);
        acc.x += a * bf2f(v.x);
        acc.y += a * bf2f(v.y);
        acc.z += a * bf2f(v.z);
        acc.w += a * bf2f(v.w);
    }
    // overflow edges (exact path; normally empty)
    if (cnt > CAP && w == 0) {
        int no = *ovfcnt; if (no > OVFCAP) no = OVFCAP;
        for (int i = 0; i < no; ++i) {
            float4 ov = ovf[i];
            if (__float_as_int(ov.x) == n) {
                int s = __float_as_int(ov.y);
                float a = h ? ov.w : ov.z;
                dn += a;
                ushort4 v = *(const ushort4*)(ftb + (size_t)s * 256 + c0);
                acc.x += a * bf2f(v.x);
                acc.y += a * bf2f(v.y);
                acc.z += a * bf2f(v.z);
                acc.w += a * bf2f(v.w);
            }
        }
    }
    *(float4*)(&red[w][c0]) = acc;
    if (l == 0)  dnw[w][0] = dn;
    if (l == 32) dnw[w][1] = dn;
    __syncthreads();
    float sum = red[0][t] + red[1][t] + red[2][t] + red[3][t];
    int th = t >> 7;
    float dtot = dnw[0][th] + dnw[1][th] + dnw[2][th] + dnw[3][th];
    float inv = dtot > 0.f ? 1.0f / dtot : 0.f;
    float r = sum * inv + feat[(size_t)n * INF + (t & 127)];
    out[(size_t)n * 256 + t] = r > 0.f ? r : expm1f(r);
}

extern "C" void kernel_launch(void* const* d_in, const int* in_sizes, int n_in,
                              void* d_out, int out_size, void* d_ws, size_t ws_size,
                              hipStream_t stream) {
    const float* feat    = (const float*)d_in[0];
    const float* e_w     = (const float*)d_in[1];
    const int*   src     = (const int*)d_in[2];
    const int*   dst     = (const int*)d_in[3];
    const float* W       = (const float*)d_in[4];
    const float* attn_l  = (const float*)d_in[5];
    const float* attn_r  = (const float*)d_in[6];
    const float* attn_ew = (const float*)d_in[7];
    float* out = (float*)d_out;

    const int N = in_sizes[0] / INF;   // 50000
    const int E = in_sizes[2];         // 800000

    // workspace carve-up (16B alignment holds for these sizes)
    unsigned short* ftb = (unsigned short*)d_ws;                 // N*256 bf16   (25.6 MB)
    float4* edata  = (float4*)(ftb + (size_t)N * 256);           // N*CAP        (25.6 MB)
    float*  elp    = (float*)(edata + (size_t)N * CAP);          // 2 * N*2
    float*  erp    = elp + (size_t)N * 4;                        // 2 * N*2
    float4* ovf    = (float4*)(erp + (size_t)N * 4);             // OVFCAP       (0.5 MB)
    int*    cursor = (int*)(ovf + OVFCAP);                       // N
    int*    ovfcnt = cursor + N;                                 // 1

    init_kernel<<<(N + 255) / 256, 256, 0, stream>>>(cursor, ovfcnt, N);

    dim3 ggrid((N + 63) / 64, 4);
    gemm_ft<<<ggrid, 256, 0, stream>>>(feat, W, attn_l, attn_r, ftb, elp, erp, N);

    edge_fused<<<(E + 255) / 256, 256, 0, stream>>>(elp, erp, e_w, src, dst, attn_ew,
                                                    cursor, ovfcnt, edata, ovf, E, N);

    aggregate<<<N, 256, 0, stream>>>(ftb, feat, edata, cursor, ovfcnt, ovf, out, N);
}

// Round 4
// 217.905 us; speedup vs baseline: 3.5507x; 1.3939x over previous
//
#include <hip/hip_runtime.h>
#include <hip/hip_bf16.h>
#include <math.h>

// Problem constants (match reference)
#define NNODES 50000
#define NEDGES 800000
#define INF 128
#define OUTF 128
#define HEADS 2
#define NEG_SLOPE 0.2f

// Padded-bin CSR: degree ~ Poisson(16); CAP=32 overflows on ~1e-4 of nodes;
// overflow edges go to a small exact-path list.
#define CAP 32
#define OVFCAP 32768

__device__ __forceinline__ unsigned short f2bf(float f) {
    unsigned u = __float_as_uint(f);
    unsigned r = (u + 0x7FFFu + ((u >> 16) & 1u)) >> 16;   // RNE
    return (unsigned short)r;
}
__device__ __forceinline__ float bf2f(unsigned short b) {
    return __uint_as_float((unsigned)b << 16);
}

typedef __attribute__((ext_vector_type(8))) short frag_ab;   // 8 bf16 (4 VGPRs)
typedef __attribute__((ext_vector_type(4))) float frag_cd;   // 4 fp32 acc

#define APITCH 136   // halfs per LDS row (272 B: 16B-aligned, odd bank stride)

// ---------- K0: init scratch (ws is poisoned 0xAA every call) ----------
__global__ void init_kernel(int* cursor, int* ovfcnt, int N) {
    int i = blockIdx.x * 256 + threadIdx.x;
    if (i < N) cursor[i] = 0;
    if (i == 0) *ovfcnt = 0;
}

// ---------- K1: MFMA gemm: ftb = bf16(feat @ Wcat^T), fused el/er partials ----------
// Block = 256 thr = 4 waves. A-tile (64 nodes x 128 k, bf16) staged once;
// B-tile (64 j x 128 k) staged per j-tile (W is L2-hot). Wave w computes rows
// w*16..w*16+15 x all 64 cols via 4 n-tiles of 16x16x32 MFMA, K in 4 chunks.
// C/D layout (verified m89/m91): col=lane&15, row=(lane>>4)*4+reg.
// el/er partials per j-tile stored to elp[n*4+jt]; edge kernel sums the 4 slots.
__global__ __launch_bounds__(256) void gemm_mfma(const float* __restrict__ feat,
                                                 const float* __restrict__ W,
                                                 const float* __restrict__ attn_l,
                                                 const float* __restrict__ attn_r,
                                                 unsigned short* __restrict__ ftb,
                                                 float* __restrict__ elp,
                                                 float* __restrict__ erp,
                                                 int N) {
    __shared__ unsigned short Asl[64 * APITCH];
    __shared__ unsigned short Bsl[64 * APITCH];
    const int t = threadIdx.x;
    const int n0 = blockIdx.x * 64;
    const int w = t >> 6, lane = t & 63;
    const int m16 = lane & 15, quad = lane >> 4;

    // stage A (feat tile) once: 64 rows x 128 k, fp32 -> bf16
#pragma unroll
    for (int i = 0; i < 8; ++i) {
        int q = t + i * 256;       // 0..2047
        int r = q >> 5;            // row 0..63
        int c4 = q & 31;           // float4 index 0..31
        int gn = n0 + r;
        float4 g = (gn < N) ? *(const float4*)(feat + (size_t)gn * INF + c4 * 4)
                            : make_float4(0.f, 0.f, 0.f, 0.f);
        ushort4 v; v.x = f2bf(g.x); v.y = f2bf(g.y); v.z = f2bf(g.z); v.w = f2bf(g.w);
        *(ushort4*)(&Asl[r * APITCH + c4 * 4]) = v;
    }

    const int arow = w * 16 + m16;

    for (int jt = 0; jt < 4; ++jt) {
        __syncthreads();   // A ready (iter 0) / previous B frag reads done
#pragma unroll
        for (int i = 0; i < 8; ++i) {
            int q = t + i * 256;
            int r = q >> 5;
            int c4 = q & 31;
            float4 g = *(const float4*)(W + (size_t)(jt * 64 + r) * INF + c4 * 4);
            ushort4 v; v.x = f2bf(g.x); v.y = f2bf(g.y); v.z = f2bf(g.z); v.w = f2bf(g.w);
            *(ushort4*)(&Bsl[r * APITCH + c4 * 4]) = v;
        }
        __syncthreads();

        frag_cd acc[4];
#pragma unroll
        for (int nt = 0; nt < 4; ++nt) acc[nt] = frag_cd{0.f, 0.f, 0.f, 0.f};

#pragma unroll
        for (int kc = 0; kc < 4; ++kc) {
            frag_ab af = *(frag_ab*)(&Asl[arow * APITCH + kc * 32 + quad * 8]);
#pragma unroll
            for (int nt = 0; nt < 4; ++nt) {
                frag_ab bf = *(frag_ab*)(&Bsl[(nt * 16 + m16) * APITCH + kc * 32 + quad * 8]);
                acc[nt] = __builtin_amdgcn_mfma_f32_16x16x32_bf16(af, bf, acc[nt], 0, 0, 0);
            }
        }

        // epilogue: ftb store + el/er partials for this j-tile
        float pl[4] = {0.f, 0.f, 0.f, 0.f};
        float pr[4] = {0.f, 0.f, 0.f, 0.f};
#pragma unroll
        for (int nt = 0; nt < 4; ++nt) {
            int gj = jt * 64 + nt * 16 + m16;       // global j (= h*128+o flat)
            float a_l = attn_l[gj];
            float a_r = attn_r[gj];
#pragma unroll
            for (int reg = 0; reg < 4; ++reg) {
                float val = acc[nt][reg];
                pl[reg] += val * a_l;
                pr[reg] += val * a_r;
                int gm = n0 + w * 16 + quad * 4 + reg;
                if (gm < N)
                    ftb[(size_t)gm * 256 + gj] = f2bf(val);
            }
        }
        // reduce pl/pr across the 16 lanes of this quad
#pragma unroll
        for (int m = 1; m < 16; m <<= 1) {
#pragma unroll
            for (int reg = 0; reg < 4; ++reg) {
                pl[reg] += __shfl_xor(pl[reg], m, 64);
                pr[reg] += __shfl_xor(pr[reg], m, 64);
            }
        }
        if (m16 == 0) {
#pragma unroll
            for (int reg = 0; reg < 4; ++reg) {
                int gm = n0 + w * 16 + quad * 4 + reg;
                if (gm < N) {
                    elp[(size_t)gm * 4 + jt] = pl[reg];
                    erp[(size_t)gm * 4 + jt] = pr[reg];
                }
            }
        }
    }
}

// ---------- K2: fused edge logits + leaky_relu + exp + padded-bin scatter ----------
// No segment-max (softmax shift-invariant; logits O(10), exp safe in fp32).
// One atomic per edge; 8-B record (src, packed bf16 ee).
__global__ void edge_fused(const float* __restrict__ elp, const float* __restrict__ erp,
                           const float* __restrict__ e_w, const int* __restrict__ src,
                           const int* __restrict__ dst, const float* __restrict__ attn_ew,
                           int* __restrict__ cursor, int* __restrict__ ovfcnt,
                           uint2* __restrict__ edata, float4* __restrict__ ovf,
                           int E) {
    int e = blockIdx.x * 256 + threadIdx.x;
    if (e >= E) return;
    int s = src[e], d = dst[e];
    float2 ew2 = *(const float2*)(e_w + (size_t)e * 2);
    float4 elv = *(const float4*)(elp + (size_t)s * 4);   // slots jt=0..3
    float4 erv = *(const float4*)(erp + (size_t)d * 4);
    float v0 = (elv.x + elv.y) + (erv.x + erv.y) + ew2.x * attn_ew[0] + ew2.y * attn_ew[1];
    float v1 = (elv.z + elv.w) + (erv.z + erv.w) + ew2.x * attn_ew[2] + ew2.y * attn_ew[3];
    v0 = v0 >= 0.f ? v0 : NEG_SLOPE * v0;
    v1 = v1 >= 0.f ? v1 : NEG_SLOPE * v1;
    float ee0 = __expf(v0);
    float ee1 = __expf(v1);
    int pos = atomicAdd(cursor + d, 1);
    if (pos < CAP) {
        unsigned pk = ((unsigned)f2bf(ee1) << 16) | (unsigned)f2bf(ee0);
        edata[(size_t)d * CAP + pos] = make_uint2((unsigned)s, pk);
    } else {
        int o = atomicAdd(ovfcnt, 1);
        if (o < OVFCAP)
            ovf[o] = make_float4(__int_as_float(d), __int_as_float(s), ee0, ee1);
    }
}

// ---------- K3: wave-per-node gather-aggregate + normalize + residual + elu ----------
// One 64-lane wave owns a node: lane l covers cols 4l..4l+3 (head = l>>5).
// Every lane accumulates the full denom itself -> no cross-lane/wave reduction,
// no barrier. Unroll-4 keeps 4 independent 512B gathers in flight.
__global__ __launch_bounds__(256) void aggregate(const unsigned short* __restrict__ ftb,
                                                 const float* __restrict__ feat,
                                                 const uint2* __restrict__ edata,
                                                 const int* __restrict__ cursor,
                                                 const int* __restrict__ ovfcnt,
                                                 const float4* __restrict__ ovf,
                                                 float* __restrict__ out, int N) {
    const int t = threadIdx.x;
    const int w = t >> 6, l = t & 63;
    const int n = blockIdx.x * 4 + w;
    if (n >= N) return;
    const int c0 = 4 * l;            // this lane's 4 cols (0..252)
    const int h = l >> 5;            // lane's head
    const int cnt = cursor[n];
    const int cmain = cnt < CAP ? cnt : CAP;
    const uint2* eb = edata + (size_t)n * CAP;

    float4 acc = make_float4(0.f, 0.f, 0.f, 0.f);
    float dn = 0.f;
#pragma unroll 4
    for (int i = 0; i < cmain; ++i) {
        uint2 rec = eb[i];
        int s = (int)rec.x;
        float a = bf2f((unsigned short)(h ? (rec.y >> 16) : (rec.y & 0xFFFFu)));
        dn += a;
        ushort4 v = *(const ushort4*)(ftb + (size_t)s * 256 + c0);
        acc.x += a * bf2f(v.x);
        acc.y += a * bf2f(v.y);
        acc.z += a * bf2f(v.z);
        acc.w += a * bf2f(v.w);
    }
    if (cnt > CAP) {   // exact overflow path (rare)
        int no = *ovfcnt; if (no > OVFCAP) no = OVFCAP;
        for (int i = 0; i < no; ++i) {
            float4 ov = ovf[i];
            if (__float_as_int(ov.x) == n) {
                int s = __float_as_int(ov.y);
                float a = h ? ov.w : ov.z;
                dn += a;
                ushort4 v = *(const ushort4*)(ftb + (size_t)s * 256 + c0);
                acc.x += a * bf2f(v.x);
                acc.y += a * bf2f(v.y);
                acc.z += a * bf2f(v.z);
                acc.w += a * bf2f(v.w);
            }
        }
    }
    float inv = dn > 0.f ? 1.0f / dn : 0.f;
    float4 f4 = *(const float4*)(feat + (size_t)n * INF + (c0 & 127));
    float4 r;
    r.x = acc.x * inv + f4.x;
    r.y = acc.y * inv + f4.y;
    r.z = acc.z * inv + f4.z;
    r.w = acc.w * inv + f4.w;
    r.x = r.x > 0.f ? r.x : expm1f(r.x);
    r.y = r.y > 0.f ? r.y : expm1f(r.y);
    r.z = r.z > 0.f ? r.z : expm1f(r.z);
    r.w = r.w > 0.f ? r.w : expm1f(r.w);
    *(float4*)(out + (size_t)n * 256 + c0) = r;
}

extern "C" void kernel_launch(void* const* d_in, const int* in_sizes, int n_in,
                              void* d_out, int out_size, void* d_ws, size_t ws_size,
                              hipStream_t stream) {
    const float* feat    = (const float*)d_in[0];
    const float* e_w     = (const float*)d_in[1];
    const int*   src     = (const int*)d_in[2];
    const int*   dst     = (const int*)d_in[3];
    const float* W       = (const float*)d_in[4];
    const float* attn_l  = (const float*)d_in[5];
    const float* attn_r  = (const float*)d_in[6];
    const float* attn_ew = (const float*)d_in[7];
    float* out = (float*)d_out;

    const int N = in_sizes[0] / INF;   // 50000
    const int E = in_sizes[2];         // 800000

    // workspace carve-up (all offsets 16B-aligned for these sizes)
    unsigned short* ftb = (unsigned short*)d_ws;                 // N*256 bf16   (25.6 MB)
    uint2*  edata  = (uint2*)(ftb + (size_t)N * 256);            // N*CAP        (12.8 MB)
    float*  elp    = (float*)(edata + (size_t)N * CAP);          // N*4          (0.8 MB)
    float*  erp    = elp + (size_t)N * 4;                        // N*4          (0.8 MB)
    float4* ovf    = (float4*)(erp + (size_t)N * 4);             // OVFCAP       (0.5 MB)
    int*    cursor = (int*)(ovf + OVFCAP);                       // N
    int*    ovfcnt = cursor + N;                                 // 1

    init_kernel<<<(N + 255) / 256, 256, 0, stream>>>(cursor, ovfcnt, N);

    gemm_mfma<<<(N + 63) / 64, 256, 0, stream>>>(feat, W, attn_l, attn_r, ftb, elp, erp, N);

    edge_fused<<<(E + 255) / 256, 256, 0, stream>>>(elp, erp, e_w, src, dst, attn_ew,
                                                    cursor, ovfcnt, edata, ovf, E);

    aggregate<<<(N + 3) / 4, 256, 0, stream>>>(ftb, feat, edata, cursor, ovfcnt, ovf, out, N);
}